// Round 1
// baseline (379.255 us; speedup 1.0000x reference)
//
#include <hip/hip_runtime.h>

#define BS 4
#define NQ 100
#define NT 25
#define NC 81
#define PIX 65536
#define QT 20        // queries per block
#define NQT 5        // q tiles (NQ/QT)
#define PC 160       // pixels per staged sub-chunk
#define KSUB 10      // sub-chunks per block
#define SPAN (PC*KSUB)   // 1600 pixels per block
#define NPB 41       // ceil(PIX / SPAN)
#define STR 164      // padded LDS row stride in floats (656B: 16B-aligned, +4 banks/row)

// ws layout (floats)
#define WS_XY 0
#define WS_SY (BS*NQ*NT)            // 10000
#define WS_SP (2*BS*NQ*NT)          // 20000
#define WS_SG (2*BS*NQ*NT + BS*NQ)  // 20400
#define WS_YT (2*BS*NQ*NT + 2*BS*NQ) // 20800
#define WS_TOTAL (2*BS*NQ*NT + 2*BS*NQ + BS*NT) // 20900

__device__ __forceinline__ float4 ld4(const float* p) {
    return *reinterpret_cast<const float4*>(p);
}
__device__ __forceinline__ void st4(float* p, float4 v) {
    *reinterpret_cast<float4*>(p) = v;
}
__device__ __forceinline__ float sigm(float x) {
    return __builtin_amdgcn_rcpf(1.0f + __expf(-x));
}

__global__ __launch_bounds__(256) void partial_kernel(
    const float* __restrict__ pm,   // [BS,NQ,PIX] mask logits
    const float* __restrict__ tm,   // [BS,NT,PIX] target masks
    float* __restrict__ ws)
{
    __shared__ float sm[(QT + QT + NT) * STR];   // 10660 floats = 42.6 KB
    float* xs = sm;
    float* gs = sm + QT * STR;
    float* ys = sm + 2 * QT * STR;

    const int tid = threadIdx.x;
    const int pb = blockIdx.x, qt = blockIdx.y, b = blockIdx.z;
    const int pbase = pb * SPAN;

    const float* xg = pm + (size_t)(b * NQ + qt * QT) * PIX;
    const float* yg = tm + (size_t)(b * NT) * PIX;

    const int slice = tid % 5;
    const int pos   = tid / 5;       // 0..49 valid
    const int qp    = pos / 5;       // 0..9
    const int tg    = pos % 5;       // 0..4
    const bool active = (tid < 250);

    float axy[2][5] = {};
    float asy[2][5] = {};
    float sp0 = 0.f, sp1 = 0.f, sg0 = 0.f, sg1 = 0.f;
    float yac[5] = {0.f, 0.f, 0.f, 0.f, 0.f};

    for (int k = 0; k < KSUB; ++k) {
        const int p0 = pbase + k * PC;
        // ---- stage x + sigmoid(x): 20 rows x 40 float4 ----
        for (int i = tid; i < QT * 40; i += 256) {
            const int row = i / 40;
            const int c   = i - row * 40;
            const int gp  = p0 + c * 4;
            float4 xv = make_float4(0.f, 0.f, 0.f, 0.f);
            float4 gv = make_float4(0.f, 0.f, 0.f, 0.f);
            if (gp < PIX) {
                xv = ld4(xg + (size_t)row * PIX + gp);
                gv.x = sigm(xv.x); gv.y = sigm(xv.y);
                gv.z = sigm(xv.z); gv.w = sigm(xv.w);
            }
            st4(xs + row * STR + c * 4, xv);
            st4(gs + row * STR + c * 4, gv);
        }
        // ---- stage y: 25 rows x 40 float4 ----
        for (int i = tid; i < NT * 40; i += 256) {
            const int row = i / 40;
            const int c   = i - row * 40;
            const int gp  = p0 + c * 4;
            float4 yv = make_float4(0.f, 0.f, 0.f, 0.f);
            if (gp < PIX) yv = ld4(yg + (size_t)row * PIX + gp);
            st4(ys + row * STR + c * 4, yv);
        }
        __syncthreads();

        if (active) {
            const float* xr0 = xs + (qp * 2) * STR;
            const float* xr1 = xr0 + STR;
            const float* gr0 = gs + (qp * 2) * STR;
            const float* gr1 = gr0 + STR;
            const float* yr  = ys + (tg * 5) * STR;
            #pragma unroll
            for (int i = 0; i < 8; ++i) {
                const int o = (slice + 5 * i) * 4;
                const float4 x0 = ld4(xr0 + o), x1 = ld4(xr1 + o);
                const float4 g0 = ld4(gr0 + o), g1 = ld4(gr1 + o);
                #pragma unroll
                for (int j = 0; j < 5; ++j) {
                    const float4 yv = ld4(yr + j * STR + o);
                    axy[0][j] = fmaf(x0.x, yv.x, fmaf(x0.y, yv.y, fmaf(x0.z, yv.z, fmaf(x0.w, yv.w, axy[0][j]))));
                    axy[1][j] = fmaf(x1.x, yv.x, fmaf(x1.y, yv.y, fmaf(x1.z, yv.z, fmaf(x1.w, yv.w, axy[1][j]))));
                    asy[0][j] = fmaf(g0.x, yv.x, fmaf(g0.y, yv.y, fmaf(g0.z, yv.z, fmaf(g0.w, yv.w, asy[0][j]))));
                    asy[1][j] = fmaf(g1.x, yv.x, fmaf(g1.y, yv.y, fmaf(g1.z, yv.z, fmaf(g1.w, yv.w, asy[1][j]))));
                    if (qp == 0) yac[j] += (yv.x + yv.y) + (yv.z + yv.w);
                }
                if (tg == 0) {
                    // softplus(x) = x - log(sigmoid(x)); padded px have g==0 -> contribute 0
                    sp0 += (g0.x > 0.f) ? (x0.x - __logf(g0.x)) : 0.f;
                    sp0 += (g0.y > 0.f) ? (x0.y - __logf(g0.y)) : 0.f;
                    sp0 += (g0.z > 0.f) ? (x0.z - __logf(g0.z)) : 0.f;
                    sp0 += (g0.w > 0.f) ? (x0.w - __logf(g0.w)) : 0.f;
                    sp1 += (g1.x > 0.f) ? (x1.x - __logf(g1.x)) : 0.f;
                    sp1 += (g1.y > 0.f) ? (x1.y - __logf(g1.y)) : 0.f;
                    sp1 += (g1.z > 0.f) ? (x1.z - __logf(g1.z)) : 0.f;
                    sp1 += (g1.w > 0.f) ? (x1.w - __logf(g1.w)) : 0.f;
                    sg0 += (g0.x + g0.y) + (g0.z + g0.w);
                    sg1 += (g1.x + g1.y) + (g1.z + g1.w);
                }
            }
        }
        __syncthreads();
    }

    // ---- block-level slice reduction, then global atomics ----
    if (active) {
        float* d = sm + tid * 20;   // 250*20 = 5000 floats
        #pragma unroll
        for (int j = 0; j < 5; ++j) {
            d[j]      = axy[0][j];
            d[5 + j]  = axy[1][j];
            d[10 + j] = asy[0][j];
            d[15 + j] = asy[1][j];
        }
        if (tg == 0) {
            float* e = sm + 5000 + (qp * 5 + slice) * 4;  // 200 floats
            e[0] = sp0; e[1] = sp1; e[2] = sg0; e[3] = sg1;
        }
        if (qp == 0) {
            float* e = sm + 5200 + (tg * 5 + slice) * 5;  // 125 floats
            #pragma unroll
            for (int j = 0; j < 5; ++j) e[j] = yac[j];
        }
    }
    __syncthreads();

    float* wxy = ws + WS_XY;
    float* wsy = ws + WS_SY;
    float* wsp = ws + WS_SP;
    float* wsg = ws + WS_SG;
    float* wyt = ws + WS_YT;

    if (tid < 50) {
        const int rqp = tid / 5, rtg = tid % 5;
        const int q0g = b * NQ + qt * QT + rqp * 2;
        const int tcol = rtg * 5;
        #pragma unroll
        for (int j = 0; j < 5; ++j) {
            float s0 = 0.f, s1 = 0.f, s2 = 0.f, s3 = 0.f;
            #pragma unroll
            for (int s5 = 0; s5 < 5; ++s5) {
                const float* src = sm + (tid * 5 + s5) * 20;
                s0 += src[j]; s1 += src[5 + j]; s2 += src[10 + j]; s3 += src[15 + j];
            }
            atomicAdd(&wxy[(size_t)q0g * NT + tcol + j], s0);
            atomicAdd(&wxy[(size_t)(q0g + 1) * NT + tcol + j], s1);
            atomicAdd(&wsy[(size_t)q0g * NT + tcol + j], s2);
            atomicAdd(&wsy[(size_t)(q0g + 1) * NT + tcol + j], s3);
        }
    }
    if (tid < 10) {
        float a0 = 0.f, a1 = 0.f, a2 = 0.f, a3 = 0.f;
        #pragma unroll
        for (int s5 = 0; s5 < 5; ++s5) {
            const float* src = sm + 5000 + (tid * 5 + s5) * 4;
            a0 += src[0]; a1 += src[1]; a2 += src[2]; a3 += src[3];
        }
        const int qg = b * NQ + qt * QT + tid * 2;
        atomicAdd(&wsp[qg], a0); atomicAdd(&wsp[qg + 1], a1);
        atomicAdd(&wsg[qg], a2); atomicAdd(&wsg[qg + 1], a3);
    }
    if (qt == 0 && tid < NT) {
        const int ttg = tid / 5, tj = tid % 5;
        float s = 0.f;
        #pragma unroll
        for (int s5 = 0; s5 < 5; ++s5)
            s += sm[5200 + (ttg * 5 + s5) * 5 + tj];
        atomicAdd(&wyt[b * NT + tid], s);
    }
}

__global__ __launch_bounds__(64) void finalize_kernel(
    const float* __restrict__ logits,  // [BS,NQ,NC]
    const int* __restrict__ labels,    // [BS,NT]
    const float* __restrict__ ws,
    float* __restrict__ out)           // [BS,NQ,NT]
{
    const int row = blockIdx.x;        // b*NQ + q
    const int b = row / NQ;
    const int lane = threadIdx.x;
    const float* lg = logits + (size_t)row * NC;

    float v0 = (lane < NC) ? lg[lane] : -1e30f;
    float v1 = (lane + 64 < NC) ? lg[lane + 64] : -1e30f;
    float mx = fmaxf(v0, v1);
    #pragma unroll
    for (int off = 32; off; off >>= 1) mx = fmaxf(mx, __shfl_xor(mx, off, 64));
    float e = ((lane < NC) ? __expf(v0 - mx) : 0.f) +
              ((lane + 64 < NC) ? __expf(v1 - mx) : 0.f);
    #pragma unroll
    for (int off = 32; off; off >>= 1) e += __shfl_xor(e, off, 64);

    if (lane < NT) {
        const int lab = labels[b * NT + lane];
        const float prob = __expf(lg[lab] - mx) / e;

        const float* wxy = ws + WS_XY;
        const float* wsy = ws + WS_SY;
        const float* wsp = ws + WS_SP;
        const float* wsg = ws + WS_SG;
        const float* wyt = ws + WS_YT;

        const float xy = wxy[(size_t)row * NT + lane];
        const float sy = wsy[(size_t)row * NT + lane];
        const float inv_p = 1.0f / (float)PIX;
        const float bce = wsp[row] * inv_p - xy * inv_p;
        const float dice = 1.0f - 2.0f * sy / (wsg[row] + wyt[b * NT + lane] + 1e-6f);
        out[(size_t)row * NT + lane] = -prob + bce + dice;
    }
}

extern "C" void kernel_launch(void* const* d_in, const int* in_sizes, int n_in,
                              void* d_out, int out_size, void* d_ws, size_t ws_size,
                              hipStream_t stream) {
    const float* pred_logits = (const float*)d_in[0];
    const float* pred_masks  = (const float*)d_in[1];
    const int*   tgt_labels  = (const int*)d_in[2];
    const float* tgt_masks   = (const float*)d_in[3];
    float* out = (float*)d_out;
    float* ws  = (float*)d_ws;

    hipMemsetAsync(d_ws, 0, WS_TOTAL * sizeof(float), stream);

    dim3 g1(NPB, NQT, BS);
    partial_kernel<<<g1, 256, 0, stream>>>(pred_masks, tgt_masks, ws);
    finalize_kernel<<<BS * NQ, 64, 0, stream>>>(pred_logits, tgt_labels, ws, out);
}

// Round 2
// 156.452 us; speedup vs baseline: 2.4241x; 2.4241x over previous
//
#include <hip/hip_runtime.h>

#define BS 4
#define NQ 100
#define NT 25
#define NC 81
#define PIX 65536
#define KCHUNK 256           // pixels per block
#define NKB (PIX / KCHUNK)   // 256 chunks per batch
#define STRB 264             // LDS y row stride in ushorts (528 B; 16B-aligned rows, 2-way banks)

// ws layout (floats)
#define WS_XY 0
#define WS_SY (BS*NQ*NT)             // 10000
#define WS_SP (2*BS*NQ*NT)           // 20000
#define WS_SG (2*BS*NQ*NT + BS*NQ)   // 20400
#define WS_YT (2*BS*NQ*NT + 2*BS*NQ) // 20800
#define WS_TOTAL (2*BS*NQ*NT + 2*BS*NQ + BS*NT) // 20900

typedef __attribute__((ext_vector_type(8))) short bf16x8;
typedef __attribute__((ext_vector_type(4))) float f32x4;

__device__ __forceinline__ float4 ld4(const float* p) {
    return *reinterpret_cast<const float4*>(p);
}
__device__ __forceinline__ short f2bf(float f) {
    union { float f; unsigned u; } v; v.f = f;
    unsigned r = v.u + 0x7FFFu + ((v.u >> 16) & 1u);
    return (short)(r >> 16);
}
__device__ __forceinline__ float bf2f(unsigned short h) {
    union { unsigned u; float f; } v; v.u = ((unsigned)h) << 16;
    return v.f;
}
__device__ __forceinline__ f32x4 mfma16(bf16x8 a, bf16x8 b, f32x4 c) {
    return __builtin_amdgcn_mfma_f32_16x16x32_bf16(a, b, c, 0, 0, 0);
}

// stable sigmoid + softplus from one exp: e=exp(-|x|), r=1/(1+e)
// sigma(x) = x>=0 ? r : 1-r ;  softplus(x) = max(x,0) - log(r)
__device__ __forceinline__ void proc8(const float4& a, const float4& b,
                                      bf16x8& fx, bf16x8& fs,
                                      float& sp, float& sg, bool valid) {
    const float xe[8] = {a.x, a.y, a.z, a.w, b.x, b.y, b.z, b.w};
    #pragma unroll
    for (int e = 0; e < 8; ++e) {
        const float x = xe[e];
        const float ee = __expf(-fabsf(x));
        const float r = __builtin_amdgcn_rcpf(1.0f + ee);
        const float sig = (x >= 0.0f) ? r : 1.0f - r;
        fx[e] = f2bf(x);
        fs[e] = f2bf(sig);
        if (valid) {
            sp += fmaxf(x, 0.0f) - __logf(r);
            sg += sig;
        }
    }
}

__global__ __launch_bounds__(256, 3) void partial_kernel(
    const float* __restrict__ pm,   // [BS,NQ,PIX] mask logits
    const float* __restrict__ tm,   // [BS,NT,PIX] target masks
    float* __restrict__ ws)
{
    __shared__ unsigned short ys[32 * STRB];   // 16.9 KB, bf16 y tile (rows 25..31 zero)

    const int tid = threadIdx.x;
    const int chunk = blockIdx.x;
    const int b = blockIdx.y;
    const int kbase = chunk * KCHUNK;

    const float* xg = pm + (size_t)b * NQ * PIX;
    const float* yg = tm + (size_t)b * NT * PIX;

    float* wxy = ws + WS_XY;
    float* wsy = ws + WS_SY;
    float* wsp = ws + WS_SP;
    float* wsg = ws + WS_SG;
    float* wyt = ws + WS_YT;

    // ---- stage y as bf16: 32 rows x KCHUNK (pad rows zero) ----
    for (int j = tid; j < 32 * (KCHUNK / 4); j += 256) {   // 2048 float4 slots
        const int t = j >> 6;
        const int c = j & 63;
        float4 yv = make_float4(0.f, 0.f, 0.f, 0.f);
        if (t < NT) yv = ld4(yg + (size_t)t * PIX + kbase + c * 4);
        ushort4 h;
        h.x = (unsigned short)f2bf(yv.x);
        h.y = (unsigned short)f2bf(yv.y);
        h.z = (unsigned short)f2bf(yv.z);
        h.w = (unsigned short)f2bf(yv.w);
        *reinterpret_cast<ushort4*>(&ys[t * STRB + c * 4]) = h;
    }
    __syncthreads();

    // ---- y row sums (from staged bf16; each k-chunk staged exactly once grid-wide) ----
    if (tid < NT * 8) {
        const int t = tid >> 3;
        const int jj = tid & 7;
        float s = 0.f;
        const unsigned short* yp = &ys[t * STRB + jj * 32];
        #pragma unroll
        for (int m = 0; m < 32; ++m) s += bf2f(yp[m]);
        s += __shfl_xor(s, 1);
        s += __shfl_xor(s, 2);
        s += __shfl_xor(s, 4);
        if (jj == 0) atomicAdd(&wyt[b * NT + t], s);
    }

    // ---- MFMA split-K main loop ----
    const int l = tid & 63;
    const int wv = tid >> 6;       // wave 0..3
    const int lrow = l & 15;       // A row / B col within tile
    const int lk = (l >> 4) * 8;   // k offset of this lane's 8 elements

    const int q0 = wv * 16 + lrow;             // tile0 rows: 0..63 (always valid)
    const int q1 = (wv + 4) * 16 + lrow;       // tile1 rows: 64..127
    const bool v1 = (q1 < NQ);
    const bool wact1 = (wv != 3);              // wave3's tile1 (rows 112..127) fully invalid

    const float* p0 = xg + (size_t)q0 * PIX + kbase + lk;
    const float* p1 = xg + (size_t)(v1 ? q1 : 0) * PIX + kbase + lk;

    f32x4 cxy[2][2] = {};
    f32x4 csy[2][2] = {};
    float spa0 = 0.f, sga0 = 0.f, spa1 = 0.f, sga1 = 0.f;

    #pragma unroll
    for (int kb = 0; kb < KCHUNK / 32; ++kb) {  // 8 k-steps of 32
        const int ko = kb * 32;

        const float4 a0 = ld4(p0 + ko);
        const float4 a1 = ld4(p0 + ko + 4);

        bf16x8 fx0, fs0;
        proc8(a0, a1, fx0, fs0, spa0, sga0, true);

        const unsigned short* yp = &ys[lrow * STRB + ko + lk];
        const bf16x8 by0 = *reinterpret_cast<const bf16x8*>(yp);
        const bf16x8 by1 = *reinterpret_cast<const bf16x8*>(yp + 16 * STRB);

        cxy[0][0] = mfma16(fx0, by0, cxy[0][0]);
        cxy[0][1] = mfma16(fx0, by1, cxy[0][1]);
        csy[0][0] = mfma16(fs0, by0, csy[0][0]);
        csy[0][1] = mfma16(fs0, by1, csy[0][1]);

        if (wact1) {
            float4 b0 = make_float4(0.f, 0.f, 0.f, 0.f);
            float4 b1 = make_float4(0.f, 0.f, 0.f, 0.f);
            if (v1) { b0 = ld4(p1 + ko); b1 = ld4(p1 + ko + 4); }
            bf16x8 fx1, fs1;
            proc8(b0, b1, fx1, fs1, spa1, sga1, v1);
            cxy[1][0] = mfma16(fx1, by0, cxy[1][0]);
            cxy[1][1] = mfma16(fx1, by1, cxy[1][1]);
            csy[1][0] = mfma16(fs1, by0, csy[1][0]);
            csy[1][1] = mfma16(fs1, by1, csy[1][1]);
        }
    }

    // ---- C partials -> global atomics (C/D map: col=lane&15, row=(lane>>4)*4+reg) ----
    #pragma unroll
    for (int i = 0; i < 2; ++i) {
        const int mt = wv + 4 * i;
        #pragma unroll
        for (int n = 0; n < 2; ++n) {
            const int t = n * 16 + lrow;
            #pragma unroll
            for (int r = 0; r < 4; ++r) {
                const int q = mt * 16 + (l >> 4) * 4 + r;
                if (q < NQ && t < NT) {
                    const size_t o = ((size_t)b * NQ + q) * NT + t;
                    atomicAdd(&wxy[o], cxy[i][n][r]);
                    atomicAdd(&wsy[o], csy[i][n][r]);
                }
            }
        }
    }

    // ---- softplus / sigma row sums: reduce lanes {l, l+16, l+32, l+48} ----
    {
        float sp = spa0, sg = sga0;
        sp += __shfl_xor(sp, 16); sp += __shfl_xor(sp, 32);
        sg += __shfl_xor(sg, 16); sg += __shfl_xor(sg, 32);
        if (l < 16) {
            const int q = wv * 16 + l;
            atomicAdd(&wsp[b * NQ + q], sp);
            atomicAdd(&wsg[b * NQ + q], sg);
        }
    }
    {
        float sp = spa1, sg = sga1;
        sp += __shfl_xor(sp, 16); sp += __shfl_xor(sp, 32);
        sg += __shfl_xor(sg, 16); sg += __shfl_xor(sg, 32);
        if (l < 16) {
            const int q = (wv + 4) * 16 + l;
            if (q < NQ) {
                atomicAdd(&wsp[b * NQ + q], sp);
                atomicAdd(&wsg[b * NQ + q], sg);
            }
        }
    }
}

__global__ __launch_bounds__(64) void finalize_kernel(
    const float* __restrict__ logits,  // [BS,NQ,NC]
    const int* __restrict__ labels,    // [BS,NT]
    const float* __restrict__ ws,
    float* __restrict__ out)           // [BS,NQ,NT]
{
    const int row = blockIdx.x;        // b*NQ + q
    const int b = row / NQ;
    const int lane = threadIdx.x;
    const float* lg = logits + (size_t)row * NC;

    float v0 = (lane < NC) ? lg[lane] : -1e30f;
    float v1 = (lane + 64 < NC) ? lg[lane + 64] : -1e30f;
    float mx = fmaxf(v0, v1);
    #pragma unroll
    for (int off = 32; off; off >>= 1) mx = fmaxf(mx, __shfl_xor(mx, off, 64));
    float e = ((lane < NC) ? __expf(v0 - mx) : 0.f) +
              ((lane + 64 < NC) ? __expf(v1 - mx) : 0.f);
    #pragma unroll
    for (int off = 32; off; off >>= 1) e += __shfl_xor(e, off, 64);

    if (lane < NT) {
        const int lab = labels[b * NT + lane];
        const float prob = __expf(lg[lab] - mx) / e;

        const float* wxy = ws + WS_XY;
        const float* wsy = ws + WS_SY;
        const float* wsp = ws + WS_SP;
        const float* wsg = ws + WS_SG;
        const float* wyt = ws + WS_YT;

        const float xy = wxy[(size_t)row * NT + lane];
        const float sy = wsy[(size_t)row * NT + lane];
        const float inv_p = 1.0f / (float)PIX;
        const float bce = wsp[row] * inv_p - xy * inv_p;
        const float dice = 1.0f - 2.0f * sy / (wsg[row] + wyt[b * NT + lane] + 1e-6f);
        out[(size_t)row * NT + lane] = -prob + bce + dice;
    }
}

extern "C" void kernel_launch(void* const* d_in, const int* in_sizes, int n_in,
                              void* d_out, int out_size, void* d_ws, size_t ws_size,
                              hipStream_t stream) {
    const float* pred_logits = (const float*)d_in[0];
    const float* pred_masks  = (const float*)d_in[1];
    const int*   tgt_labels  = (const int*)d_in[2];
    const float* tgt_masks   = (const float*)d_in[3];
    float* out = (float*)d_out;
    float* ws  = (float*)d_ws;

    hipMemsetAsync(d_ws, 0, WS_TOTAL * sizeof(float), stream);

    dim3 g1(NKB, BS);
    partial_kernel<<<g1, 256, 0, stream>>>(pred_masks, tgt_masks, ws);
    finalize_kernel<<<BS * NQ, 64, 0, stream>>>(pred_logits, tgt_labels, ws, out);
}

// Round 3
// 105.380 us; speedup vs baseline: 3.5989x; 1.4846x over previous
//
#include <hip/hip_runtime.h>

#define BS 4
#define NQ 100
#define NT 25
#define NC 81
#define PIX 65536
#define KCHUNK 256
#define NKB (PIX / KCHUNK)       // 256 chunks per batch
#define NQT 7                    // ceil(NQ/16) q-tiles
#define NWAVES (BS * NQT * NKB)  // 7168
#define NBLK (NWAVES / 4)        // 1792 blocks of 4 waves

// ws layout (floats)
#define WS_SP 0                          // BS*NQ = 400
#define WS_SG 400                        // BS*NQ = 400
#define WS_YT 800                        // BS*NT = 100
#define WS_P0 1024                       // xy partials
#define PSZ   (BS * NQT * NKB * 400)     // 2,867,200 floats (16q x 25t per wave-slot)
#define WS_P1 (WS_P0 + PSZ)
#define WS_TOTAL (WS_P1 + PSZ)           // ~22.95 MB

typedef __attribute__((ext_vector_type(8))) short bf16x8;
typedef __attribute__((ext_vector_type(4))) float f32x4;

__device__ __forceinline__ float4 ld4(const float* p) {
    return *reinterpret_cast<const float4*>(p);
}
__device__ __forceinline__ short f2bf(float f) {
    union { float f; unsigned u; } v; v.f = f;
    unsigned r = v.u + 0x7FFFu + ((v.u >> 16) & 1u);
    return (short)(r >> 16);
}
__device__ __forceinline__ f32x4 mfma16(bf16x8 a, bf16x8 b, f32x4 c) {
    return __builtin_amdgcn_mfma_f32_16x16x32_bf16(a, b, c, 0, 0, 0);
}
__device__ __forceinline__ bf16x8 pack8(const float4& a, const float4& b) {
    bf16x8 r;
    r[0] = f2bf(a.x); r[1] = f2bf(a.y); r[2] = f2bf(a.z); r[3] = f2bf(a.w);
    r[4] = f2bf(b.x); r[5] = f2bf(b.y); r[6] = f2bf(b.z); r[7] = f2bf(b.w);
    return r;
}

// stable sigmoid + softplus from one exp: e=exp(-|x|), r=1/(1+e)
// sigma(x) = x>=0 ? r : 1-r ;  softplus(x) = max(x,0) - log(r)
__device__ __forceinline__ void proc8(const float4& a, const float4& b,
                                      bf16x8& fx, bf16x8& fs,
                                      float& sp, float& sg, bool valid) {
    const float xe[8] = {a.x, a.y, a.z, a.w, b.x, b.y, b.z, b.w};
    #pragma unroll
    for (int e = 0; e < 8; ++e) {
        const float x = xe[e];
        const float ee = __expf(-fabsf(x));
        const float r = __builtin_amdgcn_rcpf(1.0f + ee);
        const float sig = (x >= 0.0f) ? r : 1.0f - r;
        fx[e] = f2bf(x);
        fs[e] = f2bf(sig);
        if (valid) {
            sp += fmaxf(x, 0.0f) - __logf(r);
            sg += sig;
        }
    }
}

__global__ __launch_bounds__(256) void partial_kernel(
    const float* __restrict__ pm,   // [BS,NQ,PIX] mask logits
    const float* __restrict__ tm,   // [BS,NT,PIX] target masks
    float* __restrict__ ws)
{
    const int tid = threadIdx.x;
    const int l = tid & 63;
    const int wid = blockIdx.x * 4 + (tid >> 6);
    const int chunk = wid & (NKB - 1);
    const int rest = wid >> 8;           // 0..27
    const int qt = rest % NQT;
    const int b = rest / NQT;
    const int kbase = chunk * KCHUNK;

    const int lrow = l & 15;
    const int lk = (l >> 4) * 8;

    const int q = qt * 16 + lrow;
    const bool qv = (q < NQ);
    const bool t1v = (lrow < NT - 16);   // second B tile col valid (lrow<9)

    const float* xp  = pm + (size_t)(b * NQ + (qv ? q : 0)) * PIX + kbase + lk;
    const float* yp0 = tm + (size_t)(b * NT + lrow) * PIX + kbase + lk;
    const float* yp1 = tm + (size_t)(b * NT + (t1v ? 16 + lrow : 0)) * PIX + kbase + lk;

    f32x4 cxy[2] = {};
    f32x4 csy[2] = {};
    float sp = 0.f, sg = 0.f, ya0 = 0.f, ya1 = 0.f;
    const bool doyt = (qt == 0);

    #pragma unroll
    for (int kb = 0; kb < KCHUNK / 32; ++kb) {
        const int ko = kb * 32;
        const float4 a0  = ld4(xp + ko);
        const float4 a1  = ld4(xp + ko + 4);
        const float4 y0a = ld4(yp0 + ko);
        const float4 y0b = ld4(yp0 + ko + 4);
        float4 y1a = make_float4(0.f, 0.f, 0.f, 0.f);
        float4 y1b = make_float4(0.f, 0.f, 0.f, 0.f);
        if (t1v) { y1a = ld4(yp1 + ko); y1b = ld4(yp1 + ko + 4); }

        bf16x8 fx, fs;
        proc8(a0, a1, fx, fs, sp, sg, qv);
        const bf16x8 by0 = pack8(y0a, y0b);
        const bf16x8 by1 = pack8(y1a, y1b);

        if (doyt) {
            ya0 += (y0a.x + y0a.y + y0a.z + y0a.w) + (y0b.x + y0b.y + y0b.z + y0b.w);
            ya1 += (y1a.x + y1a.y + y1a.z + y1a.w) + (y1b.x + y1b.y + y1b.z + y1b.w);
        }

        cxy[0] = mfma16(fx, by0, cxy[0]);
        cxy[1] = mfma16(fx, by1, cxy[1]);
        csy[0] = mfma16(fs, by0, csy[0]);
        csy[1] = mfma16(fs, by1, csy[1]);
    }

    // ---- C partials -> plain stores (C/D map: col=lane&15, row=(lane>>4)*4+reg) ----
    const size_t slot = ((size_t)(b * NQT + qt) * NKB + chunk) * 400;
    float* px = ws + WS_P0 + slot;
    float* ps = ws + WS_P1 + slot;
    #pragma unroll
    for (int n = 0; n < 2; ++n) {
        const int t = n * 16 + lrow;
        if (t < NT) {
            #pragma unroll
            for (int r = 0; r < 4; ++r) {
                const int qr = (l >> 4) * 4 + r;
                px[qr * NT + t] = cxy[n][r];
                ps[qr * NT + t] = csy[n][r];
            }
        }
    }

    // ---- softplus / sigma row sums: lanes {l, l+16, l+32, l+48} share one q ----
    sp += __shfl_xor(sp, 16); sp += __shfl_xor(sp, 32);
    sg += __shfl_xor(sg, 16); sg += __shfl_xor(sg, 32);
    if (l < 16 && qv) {
        atomicAdd(&ws[WS_SP + b * NQ + q], sp);
        atomicAdd(&ws[WS_SG + b * NQ + q], sg);
    }
    if (doyt) {
        ya0 += __shfl_xor(ya0, 16); ya0 += __shfl_xor(ya0, 32);
        ya1 += __shfl_xor(ya1, 16); ya1 += __shfl_xor(ya1, 32);
        if (l < 16) {
            atomicAdd(&ws[WS_YT + b * NT + lrow], ya0);
            if (t1v) atomicAdd(&ws[WS_YT + b * NT + 16 + lrow], ya1);
        }
    }
}

__global__ __launch_bounds__(256) void finalize_kernel(
    const float* __restrict__ logits,  // [BS,NQ,NC]
    const int* __restrict__ labels,    // [BS,NT]
    const float* __restrict__ ws,
    float* __restrict__ out)           // [BS,NQ,NT]
{
    __shared__ float s1[256];
    __shared__ float s2[256];

    const int row = blockIdx.x;        // b*NQ + q
    const int b = row / NQ, q = row % NQ;
    const int qt = q / 16, qr = q % 16;
    const int tid = threadIdx.x;
    const int t = tid & 31, cg = tid >> 5;     // 8 chunk-groups

    // ---- sum this row's (q,t) partials over 256 chunks ----
    float sxy = 0.f, ssy = 0.f;
    if (t < NT) {
        const size_t base = ((size_t)(b * NQT + qt) * NKB) * 400 + (size_t)qr * NT + t;
        const float* px = ws + WS_P0 + base;
        const float* ps = ws + WS_P1 + base;
        #pragma unroll 4
        for (int k = 0; k < NKB / 8; ++k) {
            const size_t o = (size_t)(cg + 8 * k) * 400;
            sxy += px[o];
            ssy += ps[o];
        }
    }
    s1[tid] = sxy;
    s2[tid] = ssy;
    __syncthreads();

    if (tid < 64) {
        const float* lg = logits + (size_t)row * NC;
        float v0 = (tid < NC) ? lg[tid] : -1e30f;
        float v1 = (tid + 64 < NC) ? lg[tid + 64] : -1e30f;
        float mx = fmaxf(v0, v1);
        #pragma unroll
        for (int off = 32; off; off >>= 1) mx = fmaxf(mx, __shfl_xor(mx, off, 64));
        float e = ((tid < NC) ? __expf(v0 - mx) : 0.f) +
                  ((tid + 64 < NC) ? __expf(v1 - mx) : 0.f);
        #pragma unroll
        for (int off = 32; off; off >>= 1) e += __shfl_xor(e, off, 64);

        if (tid < NT) {
            float xy = 0.f, sy = 0.f;
            #pragma unroll
            for (int g = 0; g < 8; ++g) { xy += s1[g * 32 + tid]; sy += s2[g * 32 + tid]; }

            const int lab = labels[b * NT + tid];
            const float prob = __expf(lg[lab] - mx) / e;
            const float inv_p = 1.0f / (float)PIX;
            const float bce = ws[WS_SP + row] * inv_p - xy * inv_p;
            const float dice = 1.0f - 2.0f * sy /
                               (ws[WS_SG + row] + ws[WS_YT + b * NT + tid] + 1e-6f);
            out[(size_t)row * NT + tid] = -prob + bce + dice;
        }
    }
}

extern "C" void kernel_launch(void* const* d_in, const int* in_sizes, int n_in,
                              void* d_out, int out_size, void* d_ws, size_t ws_size,
                              hipStream_t stream) {
    const float* pred_logits = (const float*)d_in[0];
    const float* pred_masks  = (const float*)d_in[1];
    const int*   tgt_labels  = (const int*)d_in[2];
    const float* tgt_masks   = (const float*)d_in[3];
    float* out = (float*)d_out;
    float* ws  = (float*)d_ws;

    // zero only the small atomic accumulators (partials are fully overwritten)
    hipMemsetAsync(d_ws, 0, 1024 * sizeof(float), stream);

    partial_kernel<<<NBLK, 256, 0, stream>>>(pred_masks, tgt_masks, ws);
    finalize_kernel<<<BS * NQ, 256, 0, stream>>>(pred_logits, tgt_labels, ws, out);
}